// Round 14
// baseline (1735.972 us; speedup 1.0000x reference)
//
#include <hip/hip_runtime.h>
#include <cstdint>
#include <cstddef>

#define NC 100000     // candidates
#define ED 768        // span-emb dim
#define HD 1024       // FFNN hidden
#define KTOP 1500     // top-k mentions
#define AA 50         // max antecedents
#define NPAIR (KTOP*AA)
#define PSTRIDE 100096
#define PSLICES 8

typedef __attribute__((ext_vector_type(8))) short v8s;    // 8 bf16
typedef __attribute__((ext_vector_type(4))) float f32x4;

__device__ __forceinline__ float relu_(float x){ return fmaxf(x, 0.f); }
__device__ __forceinline__ float bf2f(ushort h){ return __uint_as_float(((unsigned)h) << 16); }
__device__ __forceinline__ ushort f2b(float f){                 // RTNE fp32->bf16
    unsigned u = __float_as_uint(f);
    return (ushort)((u + 0x7fffu + ((u >> 16) & 1u)) >> 16);
}
__device__ __forceinline__ unsigned pack2(float a, float b){
    return (unsigned)f2b(a) | ((unsigned)f2b(b) << 16);
}
__device__ __forceinline__ unsigned fkey(float s){
    unsigned u = __float_as_uint(s);
    return (u & 0x80000000u) ? ~u : (u | 0x80000000u);
}
// bit-level sanitize: NaN -> 0, +/-inf -> +/-3e38
__device__ __forceinline__ float sanitize_(float v)
{
    unsigned bu = __float_as_uint(v);
    if ((bu & 0x7f800000u) == 0x7f800000u)
        v = (bu & 0x007fffffu) ? 0.f : ((bu >> 31) ? -3.0e38f : 3.0e38f);
    return v;
}

#define AS1(p) ((const __attribute__((address_space(1))) void*)(p))
#define AS3(p) ((__attribute__((address_space(3))) void*)(p))

// =============== bf16 MFMA GEMM: C[M,N=1024] = epi(A[M,K] @ BT[1024,K]^T) ===============
// Base: R7/R13 (1118us total, hot GEMM 256us, MfmaUtil 26%, VGPR 56+64acc=120 -> (256,4)).
// R14 DIAGNOSIS: per K-step a wave read 8x ds_read_b128 (af+bf) for 16 MFMAs =
// 512B LDS/MFMA = ~6cy at 85B/cy (m134) vs 4.85cy MFMA -> LDS-READ-BW-BOUND
// (explains R8 dbuf + R10 counted-vmcnt both neutral: they fix latency, not BW).
// FIX: B operand (weights, shared by ALL blocks on the XCD) read DIRECT from
// global - fragment addressing BT[(bn+wc+c*16+r15)*ldb + k0+q4*8] is a 16B/lane
// load; 8KB/K-step working set is L1-resident, L2 backs it (~300MB extra total).
// LDS traffic halves (af only, ~3cy/MFMA < MFMA pipe); staged loads halve;
// 8KB LDS freed. No sync-structure change.
// XCD swizzle: bid -> (xcd=bid&7, i=bid>>3, np=i&7, bmp=((i>>3)<<3)+xcd): all 8
// N-panels of an M-panel on ONE XCD (R6: FETCH 487->117MB).
// SWAPPED MFMA: acc[r][c]=mfma(bf[c],af[r],.) -> lane holds 4 consecutive n:
// packed uint2/float4 stores (R7: WRITE 400->200MB).
// A LDS XOR-swizzle: 16B chunk ^= (row>>1)&3; pre-swizzled global source, linear dest.
// EPI: 0=none(f32) 1=+bias(f32) 2=relu(+bias)(bf16)
//      3=relu(acc+U[i(p)]+V[j(p)])(bf16), p=p0+m
//      4=score: partS[np*PSTRIDE+m] = sum_{n in panel} relu(acc+bias[n])*w2[n]
template<int EPI>
__global__ __launch_bounds__(256, 4)
void bgemm_k(const ushort* __restrict__ A, int lda,
             const ushort* __restrict__ BT, int ldb,
             void* __restrict__ Cv, int ldc, int M, int Ksz, int MP,
             const float* __restrict__ bias,
             const float* __restrict__ Ub, const float* __restrict__ Vb, int p0,
             const float* __restrict__ w2, float* __restrict__ partS)
{
    const int bid = blockIdx.x;
    const int xcd = bid & 7;
    const int i0  = bid >> 3;
    const int np  = i0 & 7;
    const int bmp = ((i0 >> 3) << 3) + xcd;
    if (bmp >= MP) return;
    const int bm = bmp << 7;
    const int bn = np << 7;

    __shared__ __align__(16) ushort Al[128*32];
    __shared__ float srow[2][128];
    const int t = threadIdx.x;
    const int l = t & 63;
    const int w = t >> 6;
    const int wr = (w >> 1) << 6;
    const int wc = (w & 1) << 6;
    const int r15 = l & 15, q4 = l >> 4;
    // A staging: per-wave instr covers 16 rows x 64B; lane l -> row base+(l>>2),
    // chunk (l&3); source chunk pre-swizzled so LDS stays linear (m173 pattern)
    const int srow16 = l >> 2;
    const int schnk  = l & 3;
    // B direct-from-global row pointer base for this wave's column block
    const ushort* Bbase = BT + (size_t)(bn + wc + r15)*ldb + q4*8;

    f32x4 acc[4][4];
#pragma unroll
    for (int r = 0; r < 4; ++r)
#pragma unroll
        for (int c = 0; c < 4; ++c) acc[r][c] = (f32x4){0.f,0.f,0.f,0.f};

    for (int k0 = 0; k0 < Ksz; k0 += 32) {
        __syncthreads();                         // prev tile consumed
#pragma unroll
        for (int q = 0; q < 2; ++q) {
            int rbase = w*32 + q*16;
            int row = rbase + srow16;
            int cs = schnk ^ ((row >> 1) & 3);
            int gr = bm + row; if (gr > M-1) gr = M-1;
            __builtin_amdgcn_global_load_lds(AS1(A + (size_t)gr*lda + k0 + cs*8),
                                             AS3(Al + rbase*32), 16, 0, 0);
        }
        // B fragments direct from global (L1/L2-hot: shared across blocks)
        v8s bf[4];
#pragma unroll
        for (int c = 0; c < 4; ++c)
            bf[c] = *(const v8s*)(Bbase + (size_t)c*16*ldb + k0);
        __syncthreads();                         // A staged visible (drains vmcnt)
        v8s af[4];
#pragma unroll
        for (int r = 0; r < 4; ++r) {
            int row = wr + r*16 + r15;
            af[r] = *(const v8s*)(Al + row*32 + ((q4 ^ ((row >> 1) & 3))*8));
        }
#pragma unroll
        for (int r = 0; r < 4; ++r)
#pragma unroll
            for (int c = 0; c < 4; ++c)     // swapped operands -> C^T layout
                acc[r][c] = __builtin_amdgcn_mfma_f32_16x16x32_bf16(bf[c], af[r], acc[r][c], 0, 0, 0);
    }

    if (EPI == 4) {
        float sacc[4];
#pragma unroll
        for (int r = 0; r < 4; ++r) sacc[r] = 0.f;
#pragma unroll
        for (int c = 0; c < 4; ++c) {
            int n0 = bn + wc + c*16 + q4*4;
            const float4 bb = *(const float4*)(bias + n0);
            const float4 ww = *(const float4*)(w2 + n0);
#pragma unroll
            for (int r = 0; r < 4; ++r) {
                sacc[r] = fmaf(relu_(acc[r][c][0] + bb.x), ww.x, sacc[r]);
                sacc[r] = fmaf(relu_(acc[r][c][1] + bb.y), ww.y, sacc[r]);
                sacc[r] = fmaf(relu_(acc[r][c][2] + bb.z), ww.z, sacc[r]);
                sacc[r] = fmaf(relu_(acc[r][c][3] + bb.w), ww.w, sacc[r]);
            }
        }
        __syncthreads();
        srow[t >> 7][t & 127] = 0.f;
        __syncthreads();
#pragma unroll
        for (int r = 0; r < 4; ++r) {
            float s = sacc[r];
            s += __shfl_xor(s, 16, 64);
            s += __shfl_xor(s, 32, 64);
            if (q4 == 0) srow[w & 1][wr + r*16 + r15] = s;
        }
        __syncthreads();
        if (t < 128) {
            int m = bm + t;
            if (m < M) partS[(size_t)np*PSTRIDE + m] = srow[0][t] + srow[1][t];
        }
    } else {
        float*  Cf = (float*)Cv;
        ushort* Cb = (ushort*)Cv;
#pragma unroll
        for (int r = 0; r < 4; ++r) {
            int m = bm + wr + r*16 + r15;
            if (m >= M) continue;
            int iu = 0, iv = 0;
            if (EPI == 3) {
                int p = p0 + m;
                iu = p / 50;
                int a = p - iu*50;
                iv = iu - a - 1; if (iv < 0) iv = 0;
            }
#pragma unroll
            for (int c = 0; c < 4; ++c) {
                int n0 = bn + wc + c*16 + q4*4;
                float x0 = acc[r][c][0], x1 = acc[r][c][1];
                float x2 = acc[r][c][2], x3 = acc[r][c][3];
                if (EPI == 0) {
                    float4 o; o.x=x0; o.y=x1; o.z=x2; o.w=x3;
                    *(float4*)(Cf + (size_t)m*ldc + n0) = o;
                } else if (EPI == 1) {
                    const float4 bb = *(const float4*)(bias + n0);
                    float4 o; o.x=x0+bb.x; o.y=x1+bb.y; o.z=x2+bb.z; o.w=x3+bb.w;
                    *(float4*)(Cf + (size_t)m*ldc + n0) = o;
                } else if (EPI == 2) {
                    const float4 bb = *(const float4*)(bias + n0);
                    uint2 o;
                    o.x = pack2(relu_(x0+bb.x), relu_(x1+bb.y));
                    o.y = pack2(relu_(x2+bb.z), relu_(x3+bb.w));
                    *(uint2*)(Cb + (size_t)m*ldc + n0) = o;
                } else {
                    const float4 uu = *(const float4*)(Ub + (size_t)iu*HD + n0);
                    const float4 vv = *(const float4*)(Vb + (size_t)iv*HD + n0);
                    uint2 o;
                    o.x = pack2(relu_(x0+uu.x+vv.x), relu_(x1+uu.y+vv.y));
                    o.y = pack2(relu_(x2+uu.z+vv.z), relu_(x3+uu.w+vv.w));
                    *(uint2*)(Cb + (size_t)m*ldc + n0) = o;
                }
            }
        }
    }
}

// combine PSLICES deterministic partial-score slices + scalar bias
__global__ void comb_k(const float* __restrict__ part, const float* __restrict__ b2,
                       float* __restrict__ out, int M)
{
    int i = blockIdx.x*256 + threadIdx.x;
    if (i < M) {
        float s = b2[0];
#pragma unroll
        for (int p = 0; p < PSLICES; ++p) s += part[(size_t)p*PSTRIDE + i];
        out[i] = s;
    }
}

// =============== prep: fp32->bf16 convert; weight transpose+convert ===============
__global__ void conv_k(const float* __restrict__ src, ushort* __restrict__ dst, int n4)
{
    for (int x = blockIdx.x*blockDim.x + threadIdx.x; x < n4; x += gridDim.x*blockDim.x) {
        float4 v = ((const float4*)src)[x];
        ushort4 o; o.x = f2b(v.x); o.y = f2b(v.y); o.z = f2b(v.z); o.w = f2b(v.w);
        ((ushort4*)dst)[x] = o;
    }
}

// W [K,N] fp32 -> WT [N,K] bf16 (K,N multiples of 32)
__global__ __launch_bounds__(256)
void wt_k(const float* __restrict__ W, ushort* __restrict__ WT, int K, int N)
{
    __shared__ float ld[32][33];
    int tx = threadIdx.x & 31, ty = threadIdx.x >> 5;
    int k0 = blockIdx.y*32, n0 = blockIdx.x*32;
#pragma unroll
    for (int r = 0; r < 4; ++r)
        ld[ty + r*8][tx] = W[(size_t)(k0 + ty + r*8)*N + n0 + tx];
    __syncthreads();
#pragma unroll
    for (int r = 0; r < 4; ++r)
        WT[(size_t)(n0 + ty + r*8)*K + k0 + tx] = f2b(ld[tx][ty + r*8]);
}

// =============== exact top-k machinery (radix select, index-ordered) ===============
__global__ void init_sel_k(unsigned* state, unsigned* hist, int* top, int ntop)
{
    int t = threadIdx.x;
    if (t < 64) state[t] = 0u;
    for (int i = t; i < 1024; i += 256) hist[i] = 0u;
    for (int k = t; k < ntop; k += 256) top[k] = k;   // identity: always in-range
}

__global__ __launch_bounds__(256)
void hist_k(const float* __restrict__ scores, int N, unsigned* __restrict__ hist,
            const unsigned* __restrict__ state, int shift)
{
    __shared__ unsigned lh[256];
    lh[threadIdx.x] = 0u;
    __syncthreads();
    unsigned prefix = state[0];
    for (int i = blockIdx.x*blockDim.x + threadIdx.x; i < N; i += gridDim.x*blockDim.x) {
        unsigned u = fkey(scores[i]);
        bool ok = (shift == 24) || ((u >> (shift+8)) == prefix);
        if (ok) atomicAdd(&lh[(u >> shift) & 0xffu], 1u);
    }
    __syncthreads();
    unsigned c = lh[threadIdx.x];
    if (c) atomicAdd(&hist[threadIdx.x], c);
}

__global__ void select_k(const unsigned* __restrict__ hist, unsigned* state, int shift, int K)
{
    if (threadIdx.x != 0) return;
    unsigned P = state[1];
    unsigned acc = 0; int bstar = 0;
    for (int b = 255; b >= 0; --b) {
        unsigned h = hist[b];
        if (P + acc + h >= (unsigned)K) { bstar = b; break; }
        acc += h;
    }
    state[0] = (shift == 24) ? (unsigned)bstar : ((state[0] << 8) | (unsigned)bstar);
    state[1] = P + acc;
    if (shift == 0) state[2] = state[0];   // exact K-th key
}

__global__ __launch_bounds__(256)
void cnt_k(const float* __restrict__ scores, int N, const unsigned* __restrict__ state,
           unsigned* __restrict__ gt_cnt, unsigned* __restrict__ eq_cnt)
{
    unsigned ut = state[2];
    int base = blockIdx.x * 2048;
    unsigned g = 0, e = 0;
    for (int q = 0; q < 8; ++q) {
        int i = base + q*256 + threadIdx.x;
        if (i < N) { unsigned u = fkey(scores[i]); g += (u > ut); e += (u == ut); }
    }
    __shared__ unsigned sg[256], se[256];
    sg[threadIdx.x] = g; se[threadIdx.x] = e;
    __syncthreads();
    for (int s = 128; s > 0; s >>= 1) {
        if (threadIdx.x < s) { sg[threadIdx.x] += sg[threadIdx.x+s]; se[threadIdx.x] += se[threadIdx.x+s]; }
        __syncthreads();
    }
    if (threadIdx.x == 0) { gt_cnt[blockIdx.x] = sg[0]; eq_cnt[blockIdx.x] = se[0]; }
}

__global__ void scan_k(const unsigned* gt_cnt, const unsigned* eq_cnt,
                       unsigned* gt_off, unsigned* eq_off, int nblk, unsigned* state, int K)
{
    if (threadIdx.x != 0) return;
    unsigned ag = 0, ae = 0;
    for (int b = 0; b < nblk; ++b) {
        gt_off[b] = ag; eq_off[b] = ae;
        ag += gt_cnt[b]; ae += eq_cnt[b];
    }
    state[3] = ag;
    state[4] = ag < (unsigned)K ? (unsigned)K - ag : 0u;
}

__global__ __launch_bounds__(256)
void write_k(const float* __restrict__ scores, int N, const unsigned* __restrict__ state,
             const unsigned* __restrict__ gt_off, const unsigned* __restrict__ eq_off,
             int* __restrict__ top_idx, int Ksel)
{
    unsigned ut = state[2], T = state[4];
    int base = blockIdx.x * 2048;
    unsigned grun = gt_off[blockIdx.x], erun = eq_off[blockIdx.x];
    __shared__ unsigned wg[4], we[4];
    int t = threadIdx.x, lane = t & 63, wv = t >> 6;
    for (int q = 0; q < 8; ++q) {
        int i = base + q*256 + t;
        bool valid = i < N;
        unsigned u = valid ? fkey(scores[i]) : 0u;
        bool g = valid && (u > ut);
        bool e = valid && (u == ut);
        unsigned long long bg = __ballot(g), be = __ballot(e);
        unsigned long long lt = (1ull << lane) - 1ull;
        unsigned lpg = __popcll(bg & lt), lpe = __popcll(be & lt);
        if (lane == 0) { wg[wv] = (unsigned)__popcll(bg); we[wv] = (unsigned)__popcll(be); }
        __syncthreads();
        unsigned bsg = 0, bse = 0, tg = 0, te = 0;
        for (int ww = 0; ww < 4; ++ww) {
            if (ww < wv) { bsg += wg[ww]; bse += we[ww]; }
            tg += wg[ww]; te += we[ww];
        }
        unsigned grank = grun + bsg + lpg;
        unsigned erank = erun + bse + lpe;
        unsigned pos = 0xffffffffu;
        if (g)                   pos = grank + (erank < T ? erank : T);
        else if (e && erank < T) pos = grank + erank;
        if (pos < (unsigned)Ksel) top_idx[pos] = i;
        grun += tg; erun += te;
        __syncthreads();
    }
}

// =============== gather + bf16 convert of selected mentions ===============
__global__ void gatherF_k(const float* __restrict__ emb, const int* __restrict__ doc,
                          const int* __restrict__ topA, const float* __restrict__ scores,
                          ushort* __restrict__ meb, float* __restrict__ ms,
                          int* __restrict__ mdoc)
{
    int k = blockIdx.x;
    int idx = topA[k]; if (idx < 0 || idx >= NC) idx = 0;
    int t = threadIdx.x;
    if (t < 192) {
        float4 v = ((const float4*)(emb + (size_t)idx*ED))[t];
        ushort4 o; o.x = f2b(v.x); o.y = f2b(v.y); o.z = f2b(v.z); o.w = f2b(v.w);
        *(ushort4*)(meb + (size_t)k*ED + t*4) = o;
    }
    if (t == 192) { ms[k] = scores[idx]; mdoc[k] = doc[idx]; }
}

// elementwise bf16 products for the (tgt * ante) @ W0c term
__global__ __launch_bounds__(256)
void prodb_k(const ushort* __restrict__ meb, ushort* __restrict__ prod, int p0, int C)
{
    int tot = C * 96;   // uint4 = 8 bf16; 768/8 = 96
    for (int x = blockIdx.x*blockDim.x + threadIdx.x; x < tot; x += gridDim.x*blockDim.x) {
        int pc = x / 96, e = x - pc*96;
        int p = p0 + pc;
        int i = p / 50, a = p - i*50;
        int j = i - a - 1; if (j < 0) j = 0;
        uint4 ui = ((const uint4*)(meb + (size_t)i*ED))[e];
        uint4 uj = ((const uint4*)(meb + (size_t)j*ED))[e];
        auto pk = [](unsigned a_, unsigned b_) -> unsigned {
            float lo = bf2f((ushort)(a_ & 0xffffu)) * bf2f((ushort)(b_ & 0xffffu));
            float hi = bf2f((ushort)(a_ >> 16))     * bf2f((ushort)(b_ >> 16));
            return (unsigned)f2b(lo) | ((unsigned)f2b(hi) << 16);
        };
        uint4 o; o.x = pk(ui.x, uj.x); o.y = pk(ui.y, uj.y);
                 o.z = pk(ui.z, uj.z); o.w = pk(ui.w, uj.w);
        ((uint4*)(prod + (size_t)pc*ED))[e] = o;
    }
}

__global__ __launch_bounds__(256)
void assemble_k(const float* __restrict__ ps, const float* __restrict__ ms,
                const int* __restrict__ mdoc, float* __restrict__ out)
{
    int idx = blockIdx.x*blockDim.x + threadIdx.x;
    if (idx >= KTOP*(AA+1)) return;
    int i = idx / (AA+1), col = idx - i*(AA+1);
    if (col == 0) { out[idx] = 0.f; return; }
    int a = col - 1;
    int raw = i - a - 1;
    int j = raw < 0 ? 0 : raw;
    bool mk = (raw >= 0) && (mdoc[i] == mdoc[j]);
    float v = mk ? (ps[i*AA + a] + ms[i] + ms[j]) : -3.0e38f;  // finite sentinel
    out[idx] = sanitize_(v);
}

// ---------------------------------------------------------------------
static inline int swz_grid(int MP) { return ((MP + 7) & ~7) * 8; }

extern "C" void kernel_launch(void* const* d_in, const int* in_sizes, int n_in,
                              void* d_out, int out_size, void* d_ws, size_t ws_size,
                              hipStream_t stream)
{
    const float* emb = (const float*)d_in[0];
    const int*   doc = (const int*)d_in[1];
    const float* uw0 = (const float*)d_in[2];
    const float* ub0 = (const float*)d_in[3];
    const float* uw1 = (const float*)d_in[4];
    const float* ub1 = (const float*)d_in[5];
    const float* uw2 = (const float*)d_in[6];
    const float* ub2 = (const float*)d_in[7];
    const float* pw0 = (const float*)d_in[8];
    const float* pb0 = (const float*)d_in[9];
    const float* pw1 = (const float*)d_in[10];
    const float* pb1 = (const float*)d_in[11];
    const float* pw2 = (const float*)d_in[12];
    const float* pb2 = (const float*)d_in[13];
    float* out = (float*)d_out;

    char* ws = (char*)d_ws;
    size_t off = 0;
    auto alloc = [&](size_t bytes) -> void* {
        void* p = ws + off;
        off = (off + bytes + 255) & ~(size_t)255;
        return p;
    };
    const int NBLKA = (NC + 2047) / 2048;
    float*    scoresA = (float*)alloc((size_t)NC*4);
    float*    partS   = (float*)alloc((size_t)PSLICES*PSTRIDE*4);
    unsigned* stateA  = (unsigned*)alloc(64*4);
    unsigned* histA   = (unsigned*)alloc(1024*4);
    unsigned* gtA  = (unsigned*)alloc((size_t)NBLKA*4);
    unsigned* eqA  = (unsigned*)alloc((size_t)NBLKA*4);
    unsigned* gtoA = (unsigned*)alloc((size_t)NBLKA*4);
    unsigned* eqoA = (unsigned*)alloc((size_t)NBLKA*4);
    int*      topA = (int*)alloc((size_t)KTOP*4);
    ushort*   meb  = (ushort*)alloc((size_t)KTOP*ED*2);
    float*    ms   = (float*)alloc((size_t)KTOP*4);
    int*      mdoc = (int*)alloc((size_t)KTOP*4);
    float*    U    = (float*)alloc((size_t)KTOP*HD*4);
    float*    V    = (float*)alloc((size_t)KTOP*HD*4);
    float*    ps   = (float*)alloc((size_t)NPAIR*4);
    ushort*   uw0T = (ushort*)alloc((size_t)HD*ED*2);
    ushort*   uw1T = (ushort*)alloc((size_t)HD*HD*2);
    ushort*   paT  = (ushort*)alloc((size_t)HD*ED*2);
    ushort*   pbT  = (ushort*)alloc((size_t)HD*ED*2);
    ushort*   pcT  = (ushort*)alloc((size_t)HD*ED*2);
    ushort*   pw1T = (ushort*)alloc((size_t)HD*HD*2);
    size_t fixed = off;
    size_t avail = ws_size > fixed ? ws_size - fixed : 0;

    // ---- weight prep: transpose + bf16 convert ----
    wt_k<<<dim3(HD/32, ED/32), 256, 0, stream>>>(uw0, uw0T, ED, HD);
    wt_k<<<dim3(HD/32, HD/32), 256, 0, stream>>>(uw1, uw1T, HD, HD);
    wt_k<<<dim3(HD/32, ED/32), 256, 0, stream>>>(pw0, paT, ED, HD);
    wt_k<<<dim3(HD/32, ED/32), 256, 0, stream>>>(pw0 + (size_t)ED*HD, pbT, ED, HD);
    wt_k<<<dim3(HD/32, ED/32), 256, 0, stream>>>(pw0 + (size_t)2*ED*HD, pcT, ED, HD);
    wt_k<<<dim3(HD/32, HD/32), 256, 0, stream>>>(pw1, pw1T, HD, HD);

    // ---- unary FFNN over all candidates: L1 (EPI=2) + L2 fused score (EPI=4) ----
    {
        long Rl = (long)(avail / 3584);      // embB(1536)+H1b(2048) per row
        int R = (int)(Rl > 100096 ? 100096 : Rl);
        R &= ~127; if (R < 128) R = 128;
        ushort* embB = (ushort*)(ws + fixed);
        ushort* H1b  = embB + (size_t)R*ED;
        for (int r0 = 0; r0 < NC; r0 += R) {
            int rows = NC - r0 < R ? NC - r0 : R;
            int MP = (rows + 127)/128;
            conv_k<<<1024, 256, 0, stream>>>(emb + (size_t)r0*ED, embB, rows*192);
            bgemm_k<2><<<swz_grid(MP), 256, 0, stream>>>(embB, ED, uw0T, ED, H1b, HD,
                rows, ED, MP, ub0, nullptr, nullptr, 0, nullptr, nullptr);
            bgemm_k<4><<<swz_grid(MP), 256, 0, stream>>>(H1b, HD, uw1T, HD, nullptr, 0,
                rows, HD, MP, ub1, nullptr, nullptr, 0, uw2, partS);
            comb_k<<<(rows + 255)/256, 256, 0, stream>>>(partS, ub2, scoresA + r0, rows);
        }
    }

    // ---- exact top-KTOP selection on computed scores (ascending index order) ----
    init_sel_k<<<1, 256, 0, stream>>>(stateA, histA, topA, KTOP);
    for (int pass = 0; pass < 4; ++pass) {
        int shift = 24 - pass*8;
        hist_k<<<256, 256, 0, stream>>>(scoresA, NC, histA + pass*256, stateA, shift);
        select_k<<<1, 64, 0, stream>>>(histA + pass*256, stateA, shift, KTOP);
    }
    cnt_k<<<NBLKA, 256, 0, stream>>>(scoresA, NC, stateA, gtA, eqA);
    scan_k<<<1, 64, 0, stream>>>(gtA, eqA, gtoA, eqoA, NBLKA, stateA, KTOP);
    write_k<<<NBLKA, 256, 0, stream>>>(scoresA, NC, stateA, gtoA, eqoA, topA, KTOP);
    gatherF_k<<<KTOP, 256, 0, stream>>>(emb, doc, topA, scoresA, meb, ms, mdoc);

    // ---- per-mention parts of pair layer 0 ----
    {
        int MP = (KTOP + 127)/128;
        bgemm_k<1><<<swz_grid(MP), 256, 0, stream>>>(meb, ED, paT, ED, U, HD, KTOP, ED,
            MP, pb0, nullptr, nullptr, 0, nullptr, nullptr);
        bgemm_k<0><<<swz_grid(MP), 256, 0, stream>>>(meb, ED, pbT, ED, V, HD, KTOP, ED,
            MP, nullptr, nullptr, nullptr, 0, nullptr, nullptr);
    }

    // ---- pairwise FFNN: L0 (EPI=3) + L1 fused score (EPI=4) ----
    {
        long Cl = (long)(avail / 3584);      // prod(1536)+h0(2048) per pair
        int Cp = (int)(Cl > NPAIR ? NPAIR : Cl);
        Cp &= ~127; if (Cp < 128) Cp = 128;
        ushort* prodb = (ushort*)(ws + fixed);
        ushort* h0b = prodb + (size_t)Cp*ED;
        for (int p0 = 0; p0 < NPAIR; p0 += Cp) {
            int pc = NPAIR - p0 < Cp ? NPAIR - p0 : Cp;
            int MP = (pc + 127)/128;
            prodb_k<<<1024, 256, 0, stream>>>(meb, prodb, p0, pc);
            bgemm_k<3><<<swz_grid(MP), 256, 0, stream>>>(prodb, ED, pcT, ED, h0b, HD,
                pc, ED, MP, nullptr, U, V, p0, nullptr, nullptr);
            bgemm_k<4><<<swz_grid(MP), 256, 0, stream>>>(h0b, HD, pw1T, HD, nullptr, 0,
                pc, HD, MP, pb1, nullptr, nullptr, 0, pw2, partS);
            comb_k<<<(pc + 255)/256, 256, 0, stream>>>(partS, pb2, ps + p0, pc);
        }
    }

    // ---- final assembly ----
    assemble_k<<<(KTOP*(AA+1) + 255)/256, 256, 0, stream>>>(ps, ms, mdoc, out);
}

// Round 15
// 1020.796 us; speedup vs baseline: 1.7006x; 1.7006x over previous
//
#include <hip/hip_runtime.h>
#include <cstdint>
#include <cstddef>

#define NC 100000     // candidates
#define ED 768        // span-emb dim
#define HD 1024       // FFNN hidden
#define KTOP 1500     // top-k mentions
#define AA 50         // max antecedents
#define NPAIR (KTOP*AA)
#define PSTRIDE 100096
#define PSLICES 8

typedef __attribute__((ext_vector_type(8))) short v8s;    // 8 bf16
typedef __attribute__((ext_vector_type(4))) float f32x4;

__device__ __forceinline__ float relu_(float x){ return fmaxf(x, 0.f); }
__device__ __forceinline__ float bf2f(ushort h){ return __uint_as_float(((unsigned)h) << 16); }
__device__ __forceinline__ ushort f2b(float f){                 // RTNE fp32->bf16
    unsigned u = __float_as_uint(f);
    return (ushort)((u + 0x7fffu + ((u >> 16) & 1u)) >> 16);
}
__device__ __forceinline__ unsigned pack2(float a, float b){
    return (unsigned)f2b(a) | ((unsigned)f2b(b) << 16);
}
__device__ __forceinline__ unsigned fkey(float s){
    unsigned u = __float_as_uint(s);
    return (u & 0x80000000u) ? ~u : (u | 0x80000000u);
}
// bit-level sanitize: NaN -> 0, +/-inf -> +/-3e38
__device__ __forceinline__ float sanitize_(float v)
{
    unsigned bu = __float_as_uint(v);
    if ((bu & 0x7f800000u) == 0x7f800000u)
        v = (bu & 0x007fffffu) ? 0.f : ((bu >> 31) ? -3.0e38f : 3.0e38f);
    return v;
}

#define AS1(p) ((const __attribute__((address_space(1))) void*)(p))
#define AS3(p) ((__attribute__((address_space(3))) void*)(p))

// =============== bf16 MFMA GEMM: C[M,N=1024] = epi(A[M,K] @ BT[1024,K]^T) ===============
// Base: R13 (proven 1118us, hot 256us, MfmaUtil 26%, VGPR 56+64acc -> (256,4)).
// R14 falsified B-direct-global (16-row gather swamped L1: 19% MfmaUtil, 455us).
// THIS ROUND'S SINGLE VARIABLE: BK 32 -> 64 (m97's documented operating point for
// this exact 128^2 2-barrier structure: 874 TF). Halves barrier count per unit K
// (one vmcnt-drain per 64-K), 32 MFMA per barrier interval. LDS 16+16+1KB = 33KB
// -> 4 blocks/CU, SAME as the (256,4) VGPR cap -> no occupancy loss (the R6/R9
// failure mode). Swizzle: full chunk ^= row&7 (8 chunks/row, 2-way = free m136).
// XCD swizzle: bid -> (xcd=bid&7, i=bid>>3, np=i&7, bmp=((i>>3)<<3)+xcd): all 8
// N-panels of an M-panel on ONE XCD (R6: FETCH 487->117MB).
// SWAPPED MFMA: acc[r][c]=mfma(bf[c],af[r],.) -> lane holds 4 consecutive n:
// packed uint2/float4 stores (R7: WRITE 400->200MB).
// EPI: 0=none(f32) 1=+bias(f32) 2=relu(+bias)(bf16)
//      3=relu(acc+U[i(p)]+V[j(p)])(bf16), p=p0+m
//      4=score: partS[np*PSTRIDE+m] = sum_{n in panel} relu(acc+bias[n])*w2[n]
template<int EPI>
__global__ __launch_bounds__(256, 4)
void bgemm_k(const ushort* __restrict__ A, int lda,
             const ushort* __restrict__ BT, int ldb,
             void* __restrict__ Cv, int ldc, int M, int Ksz, int MP,
             const float* __restrict__ bias,
             const float* __restrict__ Ub, const float* __restrict__ Vb, int p0,
             const float* __restrict__ w2, float* __restrict__ partS)
{
    const int bid = blockIdx.x;
    const int xcd = bid & 7;
    const int i0  = bid >> 3;
    const int np  = i0 & 7;
    const int bmp = ((i0 >> 3) << 3) + xcd;
    if (bmp >= MP) return;
    const int bm = bmp << 7;
    const int bn = np << 7;

    __shared__ __align__(16) ushort Al[128*64];
    __shared__ __align__(16) ushort Bl[128*64];
    __shared__ float srow[2][128];
    const int t = threadIdx.x;
    const int l = t & 63;
    const int w = t >> 6;
    const int wr = (w >> 1) << 6;
    const int wc = (w & 1) << 6;
    const int r15 = l & 15, q4 = l >> 4;
    // staging (BK=64): per instr 8 rows x 128B = 1KB; lane l -> row rbase+(l>>3),
    // chunk (l&7) ^ (row&7); pre-swizzled SOURCE, linear LDS dest (m173 pattern)
    const int srow8 = l >> 3;
    const int schnk = l & 7;

    f32x4 acc[4][4];
#pragma unroll
    for (int r = 0; r < 4; ++r)
#pragma unroll
        for (int c = 0; c < 4; ++c) acc[r][c] = (f32x4){0.f,0.f,0.f,0.f};

    for (int k0 = 0; k0 < Ksz; k0 += 64) {
        __syncthreads();                         // prev tile consumed
#pragma unroll
        for (int q = 0; q < 4; ++q) {
            int rbase = w*32 + q*8;
            int row = rbase + srow8;
            int cs = schnk ^ (row & 7);
            int gr = bm + row; if (gr > M-1) gr = M-1;
            __builtin_amdgcn_global_load_lds(AS1(A + (size_t)gr*lda + k0 + cs*8),
                                             AS3(Al + rbase*64), 16, 0, 0);
            int gn = bn + row;                   // N=1024: always in-bounds
            __builtin_amdgcn_global_load_lds(AS1(BT + (size_t)gn*ldb + k0 + cs*8),
                                             AS3(Bl + rbase*64), 16, 0, 0);
        }
        __syncthreads();                         // vmcnt drained by barrier
#pragma unroll
        for (int ks = 0; ks < 2; ++ks) {
            const int clin = ks*4 + q4;          // chunk 0..7 = k offset clin*8
            v8s af[4], bf[4];
#pragma unroll
            for (int r = 0; r < 4; ++r) {
                int row = wr + r*16 + r15;
                af[r] = *(const v8s*)(Al + row*64 + ((clin ^ (row & 7))*8));
                int col = wc + r*16 + r15;
                bf[r] = *(const v8s*)(Bl + col*64 + ((clin ^ (col & 7))*8));
            }
#pragma unroll
            for (int r = 0; r < 4; ++r)
#pragma unroll
                for (int c = 0; c < 4; ++c)     // swapped operands -> C^T layout
                    acc[r][c] = __builtin_amdgcn_mfma_f32_16x16x32_bf16(bf[c], af[r], acc[r][c], 0, 0, 0);
        }
    }

    if (EPI == 4) {
        float sacc[4];
#pragma unroll
        for (int r = 0; r < 4; ++r) sacc[r] = 0.f;
#pragma unroll
        for (int c = 0; c < 4; ++c) {
            int n0 = bn + wc + c*16 + q4*4;
            const float4 bb = *(const float4*)(bias + n0);
            const float4 ww = *(const float4*)(w2 + n0);
#pragma unroll
            for (int r = 0; r < 4; ++r) {
                sacc[r] = fmaf(relu_(acc[r][c][0] + bb.x), ww.x, sacc[r]);
                sacc[r] = fmaf(relu_(acc[r][c][1] + bb.y), ww.y, sacc[r]);
                sacc[r] = fmaf(relu_(acc[r][c][2] + bb.z), ww.z, sacc[r]);
                sacc[r] = fmaf(relu_(acc[r][c][3] + bb.w), ww.w, sacc[r]);
            }
        }
        __syncthreads();
        srow[t >> 7][t & 127] = 0.f;
        __syncthreads();
#pragma unroll
        for (int r = 0; r < 4; ++r) {
            float s = sacc[r];
            s += __shfl_xor(s, 16, 64);
            s += __shfl_xor(s, 32, 64);
            if (q4 == 0) srow[w & 1][wr + r*16 + r15] = s;
        }
        __syncthreads();
        if (t < 128) {
            int m = bm + t;
            if (m < M) partS[(size_t)np*PSTRIDE + m] = srow[0][t] + srow[1][t];
        }
    } else {
        float*  Cf = (float*)Cv;
        ushort* Cb = (ushort*)Cv;
#pragma unroll
        for (int r = 0; r < 4; ++r) {
            int m = bm + wr + r*16 + r15;
            if (m >= M) continue;
            int iu = 0, iv = 0;
            if (EPI == 3) {
                int p = p0 + m;
                iu = p / 50;
                int a = p - iu*50;
                iv = iu - a - 1; if (iv < 0) iv = 0;
            }
#pragma unroll
            for (int c = 0; c < 4; ++c) {
                int n0 = bn + wc + c*16 + q4*4;
                float x0 = acc[r][c][0], x1 = acc[r][c][1];
                float x2 = acc[r][c][2], x3 = acc[r][c][3];
                if (EPI == 0) {
                    float4 o; o.x=x0; o.y=x1; o.z=x2; o.w=x3;
                    *(float4*)(Cf + (size_t)m*ldc + n0) = o;
                } else if (EPI == 1) {
                    const float4 bb = *(const float4*)(bias + n0);
                    float4 o; o.x=x0+bb.x; o.y=x1+bb.y; o.z=x2+bb.z; o.w=x3+bb.w;
                    *(float4*)(Cf + (size_t)m*ldc + n0) = o;
                } else if (EPI == 2) {
                    const float4 bb = *(const float4*)(bias + n0);
                    uint2 o;
                    o.x = pack2(relu_(x0+bb.x), relu_(x1+bb.y));
                    o.y = pack2(relu_(x2+bb.z), relu_(x3+bb.w));
                    *(uint2*)(Cb + (size_t)m*ldc + n0) = o;
                } else {
                    const float4 uu = *(const float4*)(Ub + (size_t)iu*HD + n0);
                    const float4 vv = *(const float4*)(Vb + (size_t)iv*HD + n0);
                    uint2 o;
                    o.x = pack2(relu_(x0+uu.x+vv.x), relu_(x1+uu.y+vv.y));
                    o.y = pack2(relu_(x2+uu.z+vv.z), relu_(x3+uu.w+vv.w));
                    *(uint2*)(Cb + (size_t)m*ldc + n0) = o;
                }
            }
        }
    }
}

// combine PSLICES deterministic partial-score slices + scalar bias
__global__ void comb_k(const float* __restrict__ part, const float* __restrict__ b2,
                       float* __restrict__ out, int M)
{
    int i = blockIdx.x*256 + threadIdx.x;
    if (i < M) {
        float s = b2[0];
#pragma unroll
        for (int p = 0; p < PSLICES; ++p) s += part[(size_t)p*PSTRIDE + i];
        out[i] = s;
    }
}

// =============== prep: fp32->bf16 convert; weight transpose+convert ===============
__global__ void conv_k(const float* __restrict__ src, ushort* __restrict__ dst, int n4)
{
    for (int x = blockIdx.x*blockDim.x + threadIdx.x; x < n4; x += gridDim.x*blockDim.x) {
        float4 v = ((const float4*)src)[x];
        ushort4 o; o.x = f2b(v.x); o.y = f2b(v.y); o.z = f2b(v.z); o.w = f2b(v.w);
        ((ushort4*)dst)[x] = o;
    }
}

// W [K,N] fp32 -> WT [N,K] bf16 (K,N multiples of 32)
__global__ __launch_bounds__(256)
void wt_k(const float* __restrict__ W, ushort* __restrict__ WT, int K, int N)
{
    __shared__ float ld[32][33];
    int tx = threadIdx.x & 31, ty = threadIdx.x >> 5;
    int k0 = blockIdx.y*32, n0 = blockIdx.x*32;
#pragma unroll
    for (int r = 0; r < 4; ++r)
        ld[ty + r*8][tx] = W[(size_t)(k0 + ty + r*8)*N + n0 + tx];
    __syncthreads();
#pragma unroll
    for (int r = 0; r < 4; ++r)
        WT[(size_t)(n0 + ty + r*8)*K + k0 + tx] = f2b(ld[tx][ty + r*8]);
}

// =============== exact top-k machinery (radix select, index-ordered) ===============
__global__ void init_sel_k(unsigned* state, unsigned* hist, int* top, int ntop)
{
    int t = threadIdx.x;
    if (t < 64) state[t] = 0u;
    for (int i = t; i < 1024; i += 256) hist[i] = 0u;
    for (int k = t; k < ntop; k += 256) top[k] = k;   // identity: always in-range
}

__global__ __launch_bounds__(256)
void hist_k(const float* __restrict__ scores, int N, unsigned* __restrict__ hist,
            const unsigned* __restrict__ state, int shift)
{
    __shared__ unsigned lh[256];
    lh[threadIdx.x] = 0u;
    __syncthreads();
    unsigned prefix = state[0];
    for (int i = blockIdx.x*blockDim.x + threadIdx.x; i < N; i += gridDim.x*blockDim.x) {
        unsigned u = fkey(scores[i]);
        bool ok = (shift == 24) || ((u >> (shift+8)) == prefix);
        if (ok) atomicAdd(&lh[(u >> shift) & 0xffu], 1u);
    }
    __syncthreads();
    unsigned c = lh[threadIdx.x];
    if (c) atomicAdd(&hist[threadIdx.x], c);
}

__global__ void select_k(const unsigned* __restrict__ hist, unsigned* state, int shift, int K)
{
    if (threadIdx.x != 0) return;
    unsigned P = state[1];
    unsigned acc = 0; int bstar = 0;
    for (int b = 255; b >= 0; --b) {
        unsigned h = hist[b];
        if (P + acc + h >= (unsigned)K) { bstar = b; break; }
        acc += h;
    }
    state[0] = (shift == 24) ? (unsigned)bstar : ((state[0] << 8) | (unsigned)bstar);
    state[1] = P + acc;
    if (shift == 0) state[2] = state[0];   // exact K-th key
}

__global__ __launch_bounds__(256)
void cnt_k(const float* __restrict__ scores, int N, const unsigned* __restrict__ state,
           unsigned* __restrict__ gt_cnt, unsigned* __restrict__ eq_cnt)
{
    unsigned ut = state[2];
    int base = blockIdx.x * 2048;
    unsigned g = 0, e = 0;
    for (int q = 0; q < 8; ++q) {
        int i = base + q*256 + threadIdx.x;
        if (i < N) { unsigned u = fkey(scores[i]); g += (u > ut); e += (u == ut); }
    }
    __shared__ unsigned sg[256], se[256];
    sg[threadIdx.x] = g; se[threadIdx.x] = e;
    __syncthreads();
    for (int s = 128; s > 0; s >>= 1) {
        if (threadIdx.x < s) { sg[threadIdx.x] += sg[threadIdx.x+s]; se[threadIdx.x] += se[threadIdx.x+s]; }
        __syncthreads();
    }
    if (threadIdx.x == 0) { gt_cnt[blockIdx.x] = sg[0]; eq_cnt[blockIdx.x] = se[0]; }
}

__global__ void scan_k(const unsigned* gt_cnt, const unsigned* eq_cnt,
                       unsigned* gt_off, unsigned* eq_off, int nblk, unsigned* state, int K)
{
    if (threadIdx.x != 0) return;
    unsigned ag = 0, ae = 0;
    for (int b = 0; b < nblk; ++b) {
        gt_off[b] = ag; eq_off[b] = ae;
        ag += gt_cnt[b]; ae += eq_cnt[b];
    }
    state[3] = ag;
    state[4] = ag < (unsigned)K ? (unsigned)K - ag : 0u;
}

__global__ __launch_bounds__(256)
void write_k(const float* __restrict__ scores, int N, const unsigned* __restrict__ state,
             const unsigned* __restrict__ gt_off, const unsigned* __restrict__ eq_off,
             int* __restrict__ top_idx, int Ksel)
{
    unsigned ut = state[2], T = state[4];
    int base = blockIdx.x * 2048;
    unsigned grun = gt_off[blockIdx.x], erun = eq_off[blockIdx.x];
    __shared__ unsigned wg[4], we[4];
    int t = threadIdx.x, lane = t & 63, wv = t >> 6;
    for (int q = 0; q < 8; ++q) {
        int i = base + q*256 + t;
        bool valid = i < N;
        unsigned u = valid ? fkey(scores[i]) : 0u;
        bool g = valid && (u > ut);
        bool e = valid && (u == ut);
        unsigned long long bg = __ballot(g), be = __ballot(e);
        unsigned long long lt = (1ull << lane) - 1ull;
        unsigned lpg = __popcll(bg & lt), lpe = __popcll(be & lt);
        if (lane == 0) { wg[wv] = (unsigned)__popcll(bg); we[wv] = (unsigned)__popcll(be); }
        __syncthreads();
        unsigned bsg = 0, bse = 0, tg = 0, te = 0;
        for (int ww = 0; ww < 4; ++ww) {
            if (ww < wv) { bsg += wg[ww]; bse += we[ww]; }
            tg += wg[ww]; te += we[ww];
        }
        unsigned grank = grun + bsg + lpg;
        unsigned erank = erun + bse + lpe;
        unsigned pos = 0xffffffffu;
        if (g)                   pos = grank + (erank < T ? erank : T);
        else if (e && erank < T) pos = grank + erank;
        if (pos < (unsigned)Ksel) top_idx[pos] = i;
        grun += tg; erun += te;
        __syncthreads();
    }
}

// =============== gather + bf16 convert of selected mentions ===============
__global__ void gatherF_k(const float* __restrict__ emb, const int* __restrict__ doc,
                          const int* __restrict__ topA, const float* __restrict__ scores,
                          ushort* __restrict__ meb, float* __restrict__ ms,
                          int* __restrict__ mdoc)
{
    int k = blockIdx.x;
    int idx = topA[k]; if (idx < 0 || idx >= NC) idx = 0;
    int t = threadIdx.x;
    if (t < 192) {
        float4 v = ((const float4*)(emb + (size_t)idx*ED))[t];
        ushort4 o; o.x = f2b(v.x); o.y = f2b(v.y); o.z = f2b(v.z); o.w = f2b(v.w);
        *(ushort4*)(meb + (size_t)k*ED + t*4) = o;
    }
    if (t == 192) { ms[k] = scores[idx]; mdoc[k] = doc[idx]; }
}

// elementwise bf16 products for the (tgt * ante) @ W0c term
__global__ __launch_bounds__(256)
void prodb_k(const ushort* __restrict__ meb, ushort* __restrict__ prod, int p0, int C)
{
    int tot = C * 96;   // uint4 = 8 bf16; 768/8 = 96
    for (int x = blockIdx.x*blockDim.x + threadIdx.x; x < tot; x += gridDim.x*blockDim.x) {
        int pc = x / 96, e = x - pc*96;
        int p = p0 + pc;
        int i = p / 50, a = p - i*50;
        int j = i - a - 1; if (j < 0) j = 0;
        uint4 ui = ((const uint4*)(meb + (size_t)i*ED))[e];
        uint4 uj = ((const uint4*)(meb + (size_t)j*ED))[e];
        auto pk = [](unsigned a_, unsigned b_) -> unsigned {
            float lo = bf2f((ushort)(a_ & 0xffffu)) * bf2f((ushort)(b_ & 0xffffu));
            float hi = bf2f((ushort)(a_ >> 16))     * bf2f((ushort)(b_ >> 16));
            return (unsigned)f2b(lo) | ((unsigned)f2b(hi) << 16);
        };
        uint4 o; o.x = pk(ui.x, uj.x); o.y = pk(ui.y, uj.y);
                 o.z = pk(ui.z, uj.z); o.w = pk(ui.w, uj.w);
        ((uint4*)(prod + (size_t)pc*ED))[e] = o;
    }
}

__global__ __launch_bounds__(256)
void assemble_k(const float* __restrict__ ps, const float* __restrict__ ms,
                const int* __restrict__ mdoc, float* __restrict__ out)
{
    int idx = blockIdx.x*blockDim.x + threadIdx.x;
    if (idx >= KTOP*(AA+1)) return;
    int i = idx / (AA+1), col = idx - i*(AA+1);
    if (col == 0) { out[idx] = 0.f; return; }
    int a = col - 1;
    int raw = i - a - 1;
    int j = raw < 0 ? 0 : raw;
    bool mk = (raw >= 0) && (mdoc[i] == mdoc[j]);
    float v = mk ? (ps[i*AA + a] + ms[i] + ms[j]) : -3.0e38f;  // finite sentinel
    out[idx] = sanitize_(v);
}

// ---------------------------------------------------------------------
static inline int swz_grid(int MP) { return ((MP + 7) & ~7) * 8; }

extern "C" void kernel_launch(void* const* d_in, const int* in_sizes, int n_in,
                              void* d_out, int out_size, void* d_ws, size_t ws_size,
                              hipStream_t stream)
{
    const float* emb = (const float*)d_in[0];
    const int*   doc = (const int*)d_in[1];
    const float* uw0 = (const float*)d_in[2];
    const float* ub0 = (const float*)d_in[3];
    const float* uw1 = (const float*)d_in[4];
    const float* ub1 = (const float*)d_in[5];
    const float* uw2 = (const float*)d_in[6];
    const float* ub2 = (const float*)d_in[7];
    const float* pw0 = (const float*)d_in[8];
    const float* pb0 = (const float*)d_in[9];
    const float* pw1 = (const float*)d_in[10];
    const float* pb1 = (const float*)d_in[11];
    const float* pw2 = (const float*)d_in[12];
    const float* pb2 = (const float*)d_in[13];
    float* out = (float*)d_out;

    char* ws = (char*)d_ws;
    size_t off = 0;
    auto alloc = [&](size_t bytes) -> void* {
        void* p = ws + off;
        off = (off + bytes + 255) & ~(size_t)255;
        return p;
    };
    const int NBLKA = (NC + 2047) / 2048;
    float*    scoresA = (float*)alloc((size_t)NC*4);
    float*    partS   = (float*)alloc((size_t)PSLICES*PSTRIDE*4);
    unsigned* stateA  = (unsigned*)alloc(64*4);
    unsigned* histA   = (unsigned*)alloc(1024*4);
    unsigned* gtA  = (unsigned*)alloc((size_t)NBLKA*4);
    unsigned* eqA  = (unsigned*)alloc((size_t)NBLKA*4);
    unsigned* gtoA = (unsigned*)alloc((size_t)NBLKA*4);
    unsigned* eqoA = (unsigned*)alloc((size_t)NBLKA*4);
    int*      topA = (int*)alloc((size_t)KTOP*4);
    ushort*   meb  = (ushort*)alloc((size_t)KTOP*ED*2);
    float*    ms   = (float*)alloc((size_t)KTOP*4);
    int*      mdoc = (int*)alloc((size_t)KTOP*4);
    float*    U    = (float*)alloc((size_t)KTOP*HD*4);
    float*    V    = (float*)alloc((size_t)KTOP*HD*4);
    float*    ps   = (float*)alloc((size_t)NPAIR*4);
    ushort*   uw0T = (ushort*)alloc((size_t)HD*ED*2);
    ushort*   uw1T = (ushort*)alloc((size_t)HD*HD*2);
    ushort*   paT  = (ushort*)alloc((size_t)HD*ED*2);
    ushort*   pbT  = (ushort*)alloc((size_t)HD*ED*2);
    ushort*   pcT  = (ushort*)alloc((size_t)HD*ED*2);
    ushort*   pw1T = (ushort*)alloc((size_t)HD*HD*2);
    size_t fixed = off;
    size_t avail = ws_size > fixed ? ws_size - fixed : 0;

    // ---- weight prep: transpose + bf16 convert ----
    wt_k<<<dim3(HD/32, ED/32), 256, 0, stream>>>(uw0, uw0T, ED, HD);
    wt_k<<<dim3(HD/32, HD/32), 256, 0, stream>>>(uw1, uw1T, HD, HD);
    wt_k<<<dim3(HD/32, ED/32), 256, 0, stream>>>(pw0, paT, ED, HD);
    wt_k<<<dim3(HD/32, ED/32), 256, 0, stream>>>(pw0 + (size_t)ED*HD, pbT, ED, HD);
    wt_k<<<dim3(HD/32, ED/32), 256, 0, stream>>>(pw0 + (size_t)2*ED*HD, pcT, ED, HD);
    wt_k<<<dim3(HD/32, HD/32), 256, 0, stream>>>(pw1, pw1T, HD, HD);

    // ---- unary FFNN over all candidates: L1 (EPI=2) + L2 fused score (EPI=4) ----
    {
        long Rl = (long)(avail / 3584);      // embB(1536)+H1b(2048) per row
        int R = (int)(Rl > 100096 ? 100096 : Rl);
        R &= ~127; if (R < 128) R = 128;
        ushort* embB = (ushort*)(ws + fixed);
        ushort* H1b  = embB + (size_t)R*ED;
        for (int r0 = 0; r0 < NC; r0 += R) {
            int rows = NC - r0 < R ? NC - r0 : R;
            int MP = (rows + 127)/128;
            conv_k<<<1024, 256, 0, stream>>>(emb + (size_t)r0*ED, embB, rows*192);
            bgemm_k<2><<<swz_grid(MP), 256, 0, stream>>>(embB, ED, uw0T, ED, H1b, HD,
                rows, ED, MP, ub0, nullptr, nullptr, 0, nullptr, nullptr);
            bgemm_k<4><<<swz_grid(MP), 256, 0, stream>>>(H1b, HD, uw1T, HD, nullptr, 0,
                rows, HD, MP, ub1, nullptr, nullptr, 0, uw2, partS);
            comb_k<<<(rows + 255)/256, 256, 0, stream>>>(partS, ub2, scoresA + r0, rows);
        }
    }

    // ---- exact top-KTOP selection on computed scores (ascending index order) ----
    init_sel_k<<<1, 256, 0, stream>>>(stateA, histA, topA, KTOP);
    for (int pass = 0; pass < 4; ++pass) {
        int shift = 24 - pass*8;
        hist_k<<<256, 256, 0, stream>>>(scoresA, NC, histA + pass*256, stateA, shift);
        select_k<<<1, 64, 0, stream>>>(histA + pass*256, stateA, shift, KTOP);
    }
    cnt_k<<<NBLKA, 256, 0, stream>>>(scoresA, NC, stateA, gtA, eqA);
    scan_k<<<1, 64, 0, stream>>>(gtA, eqA, gtoA, eqoA, NBLKA, stateA, KTOP);
    write_k<<<NBLKA, 256, 0, stream>>>(scoresA, NC, stateA, gtoA, eqoA, topA, KTOP);
    gatherF_k<<<KTOP, 256, 0, stream>>>(emb, doc, topA, scoresA, meb, ms, mdoc);

    // ---- per-mention parts of pair layer 0 ----
    {
        int MP = (KTOP + 127)/128;
        bgemm_k<1><<<swz_grid(MP), 256, 0, stream>>>(meb, ED, paT, ED, U, HD, KTOP, ED,
            MP, pb0, nullptr, nullptr, 0, nullptr, nullptr);
        bgemm_k<0><<<swz_grid(MP), 256, 0, stream>>>(meb, ED, pbT, ED, V, HD, KTOP, ED,
            MP, nullptr, nullptr, nullptr, 0, nullptr, nullptr);
    }

    // ---- pairwise FFNN: L0 (EPI=3) + L1 fused score (EPI=4) ----
    {
        long Cl = (long)(avail / 3584);      // prod(1536)+h0(2048) per pair
        int Cp = (int)(Cl > NPAIR ? NPAIR : Cl);
        Cp &= ~127; if (Cp < 128) Cp = 128;
        ushort* prodb = (ushort*)(ws + fixed);
        ushort* h0b = prodb + (size_t)Cp*ED;
        for (int p0 = 0; p0 < NPAIR; p0 += Cp) {
            int pc = NPAIR - p0 < Cp ? NPAIR - p0 : Cp;
            int MP = (pc + 127)/128;
            prodb_k<<<1024, 256, 0, stream>>>(meb, prodb, p0, pc);
            bgemm_k<3><<<swz_grid(MP), 256, 0, stream>>>(prodb, ED, pcT, ED, h0b, HD,
                pc, ED, MP, nullptr, U, V, p0, nullptr, nullptr);
            bgemm_k<4><<<swz_grid(MP), 256, 0, stream>>>(h0b, HD, pw1T, HD, nullptr, 0,
                pc, HD, MP, pb1, nullptr, nullptr, 0, pw2, partS);
            comb_k<<<(pc + 255)/256, 256, 0, stream>>>(partS, pb2, ps + p0, pc);
        }
    }

    // ---- final assembly ----
    assemble_k<<<(KTOP*(AA+1) + 255)/256, 256, 0, stream>>>(ps, ms, mdoc, out);
}

// Round 16
// 912.950 us; speedup vs baseline: 1.9015x; 1.1181x over previous
//
#include <hip/hip_runtime.h>
#include <cstdint>
#include <cstddef>

#define NC 100000     // candidates
#define ED 768        // span-emb dim
#define HD 1024       // FFNN hidden
#define KTOP 1500     // top-k mentions
#define AA 50         // max antecedents
#define NPAIR (KTOP*AA)
#define NBLKP ((NPAIR + 2047) / 2048)
#define PSTRIDE 100096
#define PSLICES 8

typedef __attribute__((ext_vector_type(8))) short v8s;    // 8 bf16
typedef __attribute__((ext_vector_type(4))) float f32x4;

__device__ __forceinline__ float relu_(float x){ return fmaxf(x, 0.f); }
__device__ __forceinline__ float bf2f(ushort h){ return __uint_as_float(((unsigned)h) << 16); }
__device__ __forceinline__ ushort f2b(float f){                 // RTNE fp32->bf16
    unsigned u = __float_as_uint(f);
    return (ushort)((u + 0x7fffu + ((u >> 16) & 1u)) >> 16);
}
__device__ __forceinline__ unsigned pack2(float a, float b){
    return (unsigned)f2b(a) | ((unsigned)f2b(b) << 16);
}
__device__ __forceinline__ unsigned fkey(float s){
    unsigned u = __float_as_uint(s);
    return (u & 0x80000000u) ? ~u : (u | 0x80000000u);
}
// bit-level sanitize: NaN -> 0, +/-inf -> +/-3e38
__device__ __forceinline__ float sanitize_(float v)
{
    unsigned bu = __float_as_uint(v);
    if ((bu & 0x7f800000u) == 0x7f800000u)
        v = (bu & 0x007fffffu) ? 0.f : ((bu >> 31) ? -3.0e38f : 3.0e38f);
    return v;
}

#define AS1(p) ((const __attribute__((address_space(1))) void*)(p))
#define AS3(p) ((__attribute__((address_space(3))) void*)(p))

// =============== bf16 MFMA GEMM: C[M,N=1024] = epi(A[M,K] @ BT[1024,K]^T) ===============
// R15 config (proven 1021us): 128x128 tile, BK=64 (m97 operating point), 33KB LDS,
// single buffer, 4 waves (2x2, each 64x64), 2-barrier K-loop, (256,4) — unified
// RF needs 56 arch + 64 acc regs, 4 blocks/CU is the hard cap (R11/R12 lesson).
// R16 adds PAIR COMPACTION: ~17% of pairs are masked (cross-doc / raw<0) and get
// -inf in assemble regardless; pair GEMMs now run on a compacted list. cntp/pidx:
// when cntp != nullptr, effective rows = min(*cntp - p0, M) (device count), and
// EPI=3 maps row -> original pair via pidx[p0+row]. Oversized grids early-exit.
// XCD swizzle: bid -> (xcd=bid&7, i=bid>>3, np=i&7, bmp=((i>>3)<<3)+xcd): all 8
// N-panels of an M-panel on ONE XCD (R6: FETCH 487->117MB).
// SWAPPED MFMA: acc[r][c]=mfma(bf[c],af[r],.) -> lane holds 4 consecutive n:
// packed uint2/float4 stores (R7: WRITE 400->200MB).
// LDS swizzle: chunk ^= row&7 (2-way on read = free, m136); pre-swizzled source.
// EPI: 0=none(f32) 1=+bias(f32) 2=relu(+bias)(bf16)
//      3=relu(acc+U[iu]+V[iv])(bf16), (iu,iv) from pidx[p0+m]
//      4=score: partS[np*PSTRIDE+m] = sum_{n in panel} relu(acc+bias[n])*w2[n]
template<int EPI>
__global__ __launch_bounds__(256, 4)
void bgemm_k(const ushort* __restrict__ A, int lda,
             const ushort* __restrict__ BT, int ldb,
             void* __restrict__ Cv, int ldc, int M, int Ksz, int MP,
             const float* __restrict__ bias,
             const float* __restrict__ Ub, const float* __restrict__ Vb, int p0,
             const float* __restrict__ w2, float* __restrict__ partS,
             const int* __restrict__ cntp, const int* __restrict__ pidx)
{
    const int bid = blockIdx.x;
    const int xcd = bid & 7;
    const int i0  = bid >> 3;
    const int np  = i0 & 7;
    const int bmp = ((i0 >> 3) << 3) + xcd;
    if (bmp >= MP) return;
    int Meff = M;
    if (cntp) {
        int c = *cntp - p0;
        if (c < Meff) Meff = c;
        if (Meff <= 0) return;
    }
    const int bm = bmp << 7;
    if (bm >= Meff) return;
    const int bn = np << 7;

    __shared__ __align__(16) ushort Al[128*64];
    __shared__ __align__(16) ushort Bl[128*64];
    __shared__ float srow[2][128];
    const int t = threadIdx.x;
    const int l = t & 63;
    const int w = t >> 6;
    const int wr = (w >> 1) << 6;
    const int wc = (w & 1) << 6;
    const int r15 = l & 15, q4 = l >> 4;
    // staging (BK=64): per instr 8 rows x 128B = 1KB; lane l -> row rbase+(l>>3),
    // chunk (l&7) ^ (row&7); pre-swizzled SOURCE, linear LDS dest (m173 pattern)
    const int srow8 = l >> 3;
    const int schnk = l & 7;

    f32x4 acc[4][4];
#pragma unroll
    for (int r = 0; r < 4; ++r)
#pragma unroll
        for (int c = 0; c < 4; ++c) acc[r][c] = (f32x4){0.f,0.f,0.f,0.f};

    for (int k0 = 0; k0 < Ksz; k0 += 64) {
        __syncthreads();                         // prev tile consumed
#pragma unroll
        for (int q = 0; q < 4; ++q) {
            int rbase = w*32 + q*8;
            int row = rbase + srow8;
            int cs = schnk ^ (row & 7);
            int gr = bm + row; if (gr > Meff-1) gr = Meff-1;
            __builtin_amdgcn_global_load_lds(AS1(A + (size_t)gr*lda + k0 + cs*8),
                                             AS3(Al + rbase*64), 16, 0, 0);
            int gn = bn + row;                   // N=1024: always in-bounds
            __builtin_amdgcn_global_load_lds(AS1(BT + (size_t)gn*ldb + k0 + cs*8),
                                             AS3(Bl + rbase*64), 16, 0, 0);
        }
        __syncthreads();                         // vmcnt drained by barrier
#pragma unroll
        for (int ks = 0; ks < 2; ++ks) {
            const int clin = ks*4 + q4;          // chunk 0..7 = k offset clin*8
            v8s af[4], bf[4];
#pragma unroll
            for (int r = 0; r < 4; ++r) {
                int row = wr + r*16 + r15;
                af[r] = *(const v8s*)(Al + row*64 + ((clin ^ (row & 7))*8));
                int col = wc + r*16 + r15;
                bf[r] = *(const v8s*)(Bl + col*64 + ((clin ^ (col & 7))*8));
            }
#pragma unroll
            for (int r = 0; r < 4; ++r)
#pragma unroll
                for (int c = 0; c < 4; ++c)     // swapped operands -> C^T layout
                    acc[r][c] = __builtin_amdgcn_mfma_f32_16x16x32_bf16(bf[c], af[r], acc[r][c], 0, 0, 0);
        }
    }

    if (EPI == 4) {
        float sacc[4];
#pragma unroll
        for (int r = 0; r < 4; ++r) sacc[r] = 0.f;
#pragma unroll
        for (int c = 0; c < 4; ++c) {
            int n0 = bn + wc + c*16 + q4*4;
            const float4 bb = *(const float4*)(bias + n0);
            const float4 ww = *(const float4*)(w2 + n0);
#pragma unroll
            for (int r = 0; r < 4; ++r) {
                sacc[r] = fmaf(relu_(acc[r][c][0] + bb.x), ww.x, sacc[r]);
                sacc[r] = fmaf(relu_(acc[r][c][1] + bb.y), ww.y, sacc[r]);
                sacc[r] = fmaf(relu_(acc[r][c][2] + bb.z), ww.z, sacc[r]);
                sacc[r] = fmaf(relu_(acc[r][c][3] + bb.w), ww.w, sacc[r]);
            }
        }
        __syncthreads();
        srow[t >> 7][t & 127] = 0.f;
        __syncthreads();
#pragma unroll
        for (int r = 0; r < 4; ++r) {
            float s = sacc[r];
            s += __shfl_xor(s, 16, 64);
            s += __shfl_xor(s, 32, 64);
            if (q4 == 0) srow[w & 1][wr + r*16 + r15] = s;
        }
        __syncthreads();
        if (t < 128) {
            int m = bm + t;
            if (m < Meff) partS[(size_t)np*PSTRIDE + m] = srow[0][t] + srow[1][t];
        }
    } else {
        float*  Cf = (float*)Cv;
        ushort* Cb = (ushort*)Cv;
#pragma unroll
        for (int r = 0; r < 4; ++r) {
            int m = bm + wr + r*16 + r15;
            if (m >= Meff) continue;
            int iu = 0, iv = 0;
            if (EPI == 3) {
                int p = pidx[p0 + m];
                iu = p / 50;
                int a = p - iu*50;
                iv = iu - a - 1; if (iv < 0) iv = 0;
            }
#pragma unroll
            for (int c = 0; c < 4; ++c) {
                int n0 = bn + wc + c*16 + q4*4;
                float x0 = acc[r][c][0], x1 = acc[r][c][1];
                float x2 = acc[r][c][2], x3 = acc[r][c][3];
                if (EPI == 0) {
                    float4 o; o.x=x0; o.y=x1; o.z=x2; o.w=x3;
                    *(float4*)(Cf + (size_t)m*ldc + n0) = o;
                } else if (EPI == 1) {
                    const float4 bb = *(const float4*)(bias + n0);
                    float4 o; o.x=x0+bb.x; o.y=x1+bb.y; o.z=x2+bb.z; o.w=x3+bb.w;
                    *(float4*)(Cf + (size_t)m*ldc + n0) = o;
                } else if (EPI == 2) {
                    const float4 bb = *(const float4*)(bias + n0);
                    uint2 o;
                    o.x = pack2(relu_(x0+bb.x), relu_(x1+bb.y));
                    o.y = pack2(relu_(x2+bb.z), relu_(x3+bb.w));
                    *(uint2*)(Cb + (size_t)m*ldc + n0) = o;
                } else {
                    const float4 uu = *(const float4*)(Ub + (size_t)iu*HD + n0);
                    const float4 vv = *(const float4*)(Vb + (size_t)iv*HD + n0);
                    uint2 o;
                    o.x = pack2(relu_(x0+uu.x+vv.x), relu_(x1+uu.y+vv.y));
                    o.y = pack2(relu_(x2+uu.z+vv.z), relu_(x3+uu.w+vv.w));
                    *(uint2*)(Cb + (size_t)m*ldc + n0) = o;
                }
            }
        }
    }
}

// combine PSLICES partial-score slices + scalar bias (unary: dense rows)
__global__ void comb_k(const float* __restrict__ part, const float* __restrict__ b2,
                       float* __restrict__ out, int M)
{
    int i = blockIdx.x*256 + threadIdx.x;
    if (i < M) {
        float s = b2[0];
#pragma unroll
        for (int p = 0; p < PSLICES; ++p) s += part[(size_t)p*PSTRIDE + i];
        out[i] = s;
    }
}

// pair variant: compacted row i -> scatter to ps[pidx[p0+i]]
__global__ void combp_k(const float* __restrict__ part, const float* __restrict__ b2,
                        float* __restrict__ ps, int Cp, int p0,
                        const int* __restrict__ cntp, const int* __restrict__ pidx)
{
    int i = blockIdx.x*256 + threadIdx.x;
    int Meff = *cntp - p0; if (Meff > Cp) Meff = Cp;
    if (i < Meff) {
        float s = b2[0];
#pragma unroll
        for (int p = 0; p < PSLICES; ++p) s += part[(size_t)p*PSTRIDE + i];
        ps[pidx[p0 + i]] = s;
    }
}

// =============== prep: fp32->bf16 convert; weight transpose+convert ===============
__global__ void conv_k(const float* __restrict__ src, ushort* __restrict__ dst, int n4)
{
    for (int x = blockIdx.x*blockDim.x + threadIdx.x; x < n4; x += gridDim.x*blockDim.x) {
        float4 v = ((const float4*)src)[x];
        ushort4 o; o.x = f2b(v.x); o.y = f2b(v.y); o.z = f2b(v.z); o.w = f2b(v.w);
        ((ushort4*)dst)[x] = o;
    }
}

// W [K,N] fp32 -> WT [N,K] bf16 (K,N multiples of 32)
__global__ __launch_bounds__(256)
void wt_k(const float* __restrict__ W, ushort* __restrict__ WT, int K, int N)
{
    __shared__ float ld[32][33];
    int tx = threadIdx.x & 31, ty = threadIdx.x >> 5;
    int k0 = blockIdx.y*32, n0 = blockIdx.x*32;
#pragma unroll
    for (int r = 0; r < 4; ++r)
        ld[ty + r*8][tx] = W[(size_t)(k0 + ty + r*8)*N + n0 + tx];
    __syncthreads();
#pragma unroll
    for (int r = 0; r < 4; ++r)
        WT[(size_t)(n0 + ty + r*8)*K + k0 + tx] = f2b(ld[tx][ty + r*8]);
}

// =============== exact top-k machinery (radix select, index-ordered) ===============
__global__ void init_sel_k(unsigned* state, unsigned* hist, int* top, int ntop)
{
    int t = threadIdx.x;
    if (t < 64) state[t] = 0u;
    for (int i = t; i < 1024; i += 256) hist[i] = 0u;
    for (int k = t; k < ntop; k += 256) top[k] = k;   // identity: always in-range
}

__global__ __launch_bounds__(256)
void hist_k(const float* __restrict__ scores, int N, unsigned* __restrict__ hist,
            const unsigned* __restrict__ state, int shift)
{
    __shared__ unsigned lh[256];
    lh[threadIdx.x] = 0u;
    __syncthreads();
    unsigned prefix = state[0];
    for (int i = blockIdx.x*blockDim.x + threadIdx.x; i < N; i += gridDim.x*blockDim.x) {
        unsigned u = fkey(scores[i]);
        bool ok = (shift == 24) || ((u >> (shift+8)) == prefix);
        if (ok) atomicAdd(&lh[(u >> shift) & 0xffu], 1u);
    }
    __syncthreads();
    unsigned c = lh[threadIdx.x];
    if (c) atomicAdd(&hist[threadIdx.x], c);
}

__global__ void select_k(const unsigned* __restrict__ hist, unsigned* state, int shift, int K)
{
    if (threadIdx.x != 0) return;
    unsigned P = state[1];
    unsigned acc = 0; int bstar = 0;
    for (int b = 255; b >= 0; --b) {
        unsigned h = hist[b];
        if (P + acc + h >= (unsigned)K) { bstar = b; break; }
        acc += h;
    }
    state[0] = (shift == 24) ? (unsigned)bstar : ((state[0] << 8) | (unsigned)bstar);
    state[1] = P + acc;
    if (shift == 0) state[2] = state[0];   // exact K-th key
}

__global__ __launch_bounds__(256)
void cnt_k(const float* __restrict__ scores, int N, const unsigned* __restrict__ state,
           unsigned* __restrict__ gt_cnt, unsigned* __restrict__ eq_cnt)
{
    unsigned ut = state[2];
    int base = blockIdx.x * 2048;
    unsigned g = 0, e = 0;
    for (int q = 0; q < 8; ++q) {
        int i = base + q*256 + threadIdx.x;
        if (i < N) { unsigned u = fkey(scores[i]); g += (u > ut); e += (u == ut); }
    }
    __shared__ unsigned sg[256], se[256];
    sg[threadIdx.x] = g; se[threadIdx.x] = e;
    __syncthreads();
    for (int s = 128; s > 0; s >>= 1) {
        if (threadIdx.x < s) { sg[threadIdx.x] += sg[threadIdx.x+s]; se[threadIdx.x] += se[threadIdx.x+s]; }
        __syncthreads();
    }
    if (threadIdx.x == 0) { gt_cnt[blockIdx.x] = sg[0]; eq_cnt[blockIdx.x] = se[0]; }
}

__global__ void scan_k(const unsigned* gt_cnt, const unsigned* eq_cnt,
                       unsigned* gt_off, unsigned* eq_off, int nblk, unsigned* state, int K)
{
    if (threadIdx.x != 0) return;
    unsigned ag = 0, ae = 0;
    for (int b = 0; b < nblk; ++b) {
        gt_off[b] = ag; eq_off[b] = ae;
        ag += gt_cnt[b]; ae += eq_cnt[b];
    }
    state[3] = ag;
    state[4] = ag < (unsigned)K ? (unsigned)K - ag : 0u;
}

__global__ __launch_bounds__(256)
void write_k(const float* __restrict__ scores, int N, const unsigned* __restrict__ state,
             const unsigned* __restrict__ gt_off, const unsigned* __restrict__ eq_off,
             int* __restrict__ top_idx, int Ksel)
{
    unsigned ut = state[2], T = state[4];
    int base = blockIdx.x * 2048;
    unsigned grun = gt_off[blockIdx.x], erun = eq_off[blockIdx.x];
    __shared__ unsigned wg[4], we[4];
    int t = threadIdx.x, lane = t & 63, wv = t >> 6;
    for (int q = 0; q < 8; ++q) {
        int i = base + q*256 + t;
        bool valid = i < N;
        unsigned u = valid ? fkey(scores[i]) : 0u;
        bool g = valid && (u > ut);
        bool e = valid && (u == ut);
        unsigned long long bg = __ballot(g), be = __ballot(e);
        unsigned long long lt = (1ull << lane) - 1ull;
        unsigned lpg = __popcll(bg & lt), lpe = __popcll(be & lt);
        if (lane == 0) { wg[wv] = (unsigned)__popcll(bg); we[wv] = (unsigned)__popcll(be); }
        __syncthreads();
        unsigned bsg = 0, bse = 0, tg = 0, te = 0;
        for (int ww = 0; ww < 4; ++ww) {
            if (ww < wv) { bsg += wg[ww]; bse += we[ww]; }
            tg += wg[ww]; te += we[ww];
        }
        unsigned grank = grun + bsg + lpg;
        unsigned erank = erun + bse + lpe;
        unsigned pos = 0xffffffffu;
        if (g)                   pos = grank + (erank < T ? erank : T);
        else if (e && erank < T) pos = grank + erank;
        if (pos < (unsigned)Ksel) top_idx[pos] = i;
        grun += tg; erun += te;
        __syncthreads();
    }
}

// =============== gather + bf16 convert of selected mentions ===============
__global__ void gatherF_k(const float* __restrict__ emb, const int* __restrict__ doc,
                          const int* __restrict__ topA, const float* __restrict__ scores,
                          ushort* __restrict__ meb, float* __restrict__ ms,
                          int* __restrict__ mdoc)
{
    int k = blockIdx.x;
    int idx = topA[k]; if (idx < 0 || idx >= NC) idx = 0;
    int t = threadIdx.x;
    if (t < 192) {
        float4 v = ((const float4*)(emb + (size_t)idx*ED))[t];
        ushort4 o; o.x = f2b(v.x); o.y = f2b(v.y); o.z = f2b(v.z); o.w = f2b(v.w);
        *(ushort4*)(meb + (size_t)k*ED + t*4) = o;
    }
    if (t == 192) { ms[k] = scores[idx]; mdoc[k] = doc[idx]; }
}

// =============== pair compaction (valid = in-window && same-doc) ===============
__device__ __forceinline__ bool pvalid_(int p, const int* __restrict__ mdoc)
{
    int i = p / 50, a = p - i*50;
    int j = i - a - 1;
    return (j >= 0) && (mdoc[i] == mdoc[j]);
}

__global__ __launch_bounds__(256)
void pcnt_k(const int* __restrict__ mdoc, unsigned* __restrict__ blk_cnt)
{
    int base = blockIdx.x * 2048;
    unsigned c = 0;
    for (int q = 0; q < 8; ++q) {
        int p = base + q*256 + threadIdx.x;
        if (p < NPAIR && pvalid_(p, mdoc)) ++c;
    }
    __shared__ unsigned sc[256];
    sc[threadIdx.x] = c;
    __syncthreads();
    for (int s = 128; s > 0; s >>= 1) {
        if (threadIdx.x < s) sc[threadIdx.x] += sc[threadIdx.x + s];
        __syncthreads();
    }
    if (threadIdx.x == 0) blk_cnt[blockIdx.x] = sc[0];
}

__global__ void pscan_k(const unsigned* __restrict__ blk_cnt,
                        unsigned* __restrict__ blk_off, int* __restrict__ pcnt)
{
    if (threadIdx.x != 0) return;
    unsigned a = 0;
    for (int b = 0; b < NBLKP; ++b) { blk_off[b] = a; a += blk_cnt[b]; }
    pcnt[0] = (int)a;
}

__global__ __launch_bounds__(256)
void pwrite_k(const int* __restrict__ mdoc, const unsigned* __restrict__ blk_off,
              int* __restrict__ pidx)
{
    int base = blockIdx.x * 2048;
    unsigned run = blk_off[blockIdx.x];
    __shared__ unsigned wcnt[4];
    int t = threadIdx.x, lane = t & 63, wv = t >> 6;
    for (int q = 0; q < 8; ++q) {
        int p = base + q*256 + t;
        bool v = (p < NPAIR) && pvalid_(p, mdoc);
        unsigned long long bv = __ballot(v);
        unsigned long long lt = (1ull << lane) - 1ull;
        unsigned lp = __popcll(bv & lt);
        if (lane == 0) wcnt[wv] = (unsigned)__popcll(bv);
        __syncthreads();
        unsigned bs = 0, tot = 0;
        for (int ww = 0; ww < 4; ++ww) {
            if (ww < wv) bs += wcnt[ww];
            tot += wcnt[ww];
        }
        if (v) pidx[run + bs + lp] = p;   // ascending-p deterministic order
        run += tot;
        __syncthreads();
    }
}

// elementwise bf16 products, compacted: row pc -> pair pidx[p0+pc]
__global__ __launch_bounds__(256)
void prodb_k(const ushort* __restrict__ meb, ushort* __restrict__ prod, int p0, int Cp,
             const int* __restrict__ cntp, const int* __restrict__ pidx)
{
    int Meff = *cntp - p0; if (Meff > Cp) Meff = Cp;
    if (Meff <= 0) return;
    int tot = Meff * 96;   // uint4 = 8 bf16; 768/8 = 96
    for (int x = blockIdx.x*blockDim.x + threadIdx.x; x < tot; x += gridDim.x*blockDim.x) {
        int pc = x / 96, e = x - pc*96;
        int p = pidx[p0 + pc];
        int i = p / 50, a = p - i*50;
        int j = i - a - 1; if (j < 0) j = 0;
        uint4 ui = ((const uint4*)(meb + (size_t)i*ED))[e];
        uint4 uj = ((const uint4*)(meb + (size_t)j*ED))[e];
        auto pk = [](unsigned a_, unsigned b_) -> unsigned {
            float lo = bf2f((ushort)(a_ & 0xffffu)) * bf2f((ushort)(b_ & 0xffffu));
            float hi = bf2f((ushort)(a_ >> 16))     * bf2f((ushort)(b_ >> 16));
            return (unsigned)f2b(lo) | ((unsigned)f2b(hi) << 16);
        };
        uint4 o; o.x = pk(ui.x, uj.x); o.y = pk(ui.y, uj.y);
                 o.z = pk(ui.z, uj.z); o.w = pk(ui.w, uj.w);
        ((uint4*)(prod + (size_t)pc*ED))[e] = o;
    }
}

__global__ __launch_bounds__(256)
void assemble_k(const float* __restrict__ ps, const float* __restrict__ ms,
                const int* __restrict__ mdoc, float* __restrict__ out)
{
    int idx = blockIdx.x*blockDim.x + threadIdx.x;
    if (idx >= KTOP*(AA+1)) return;
    int i = idx / (AA+1), col = idx - i*(AA+1);
    if (col == 0) { out[idx] = 0.f; return; }
    int a = col - 1;
    int raw = i - a - 1;
    int j = raw < 0 ? 0 : raw;
    bool mk = (raw >= 0) && (mdoc[i] == mdoc[j]);
    float v = mk ? (ps[i*AA + a] + ms[i] + ms[j]) : -3.0e38f;  // finite sentinel
    out[idx] = sanitize_(v);
}

// ---------------------------------------------------------------------
static inline int swz_grid(int MP) { return ((MP + 7) & ~7) * 8; }

extern "C" void kernel_launch(void* const* d_in, const int* in_sizes, int n_in,
                              void* d_out, int out_size, void* d_ws, size_t ws_size,
                              hipStream_t stream)
{
    const float* emb = (const float*)d_in[0];
    const int*   doc = (const int*)d_in[1];
    const float* uw0 = (const float*)d_in[2];
    const float* ub0 = (const float*)d_in[3];
    const float* uw1 = (const float*)d_in[4];
    const float* ub1 = (const float*)d_in[5];
    const float* uw2 = (const float*)d_in[6];
    const float* ub2 = (const float*)d_in[7];
    const float* pw0 = (const float*)d_in[8];
    const float* pb0 = (const float*)d_in[9];
    const float* pw1 = (const float*)d_in[10];
    const float* pb1 = (const float*)d_in[11];
    const float* pw2 = (const float*)d_in[12];
    const float* pb2 = (const float*)d_in[13];
    float* out = (float*)d_out;

    char* ws = (char*)d_ws;
    size_t off = 0;
    auto alloc = [&](size_t bytes) -> void* {
        void* p = ws + off;
        off = (off + bytes + 255) & ~(size_t)255;
        return p;
    };
    const int NBLKA = (NC + 2047) / 2048;
    float*    scoresA = (float*)alloc((size_t)NC*4);
    float*    partS   = (float*)alloc((size_t)PSLICES*PSTRIDE*4);
    unsigned* stateA  = (unsigned*)alloc(64*4);
    unsigned* histA   = (unsigned*)alloc(1024*4);
    unsigned* gtA  = (unsigned*)alloc((size_t)NBLKA*4);
    unsigned* eqA  = (unsigned*)alloc((size_t)NBLKA*4);
    unsigned* gtoA = (unsigned*)alloc((size_t)NBLKA*4);
    unsigned* eqoA = (unsigned*)alloc((size_t)NBLKA*4);
    int*      topA = (int*)alloc((size_t)KTOP*4);
    ushort*   meb  = (ushort*)alloc((size_t)KTOP*ED*2);
    float*    ms   = (float*)alloc((size_t)KTOP*4);
    int*      mdoc = (int*)alloc((size_t)KTOP*4);
    float*    U    = (float*)alloc((size_t)KTOP*HD*4);
    float*    V    = (float*)alloc((size_t)KTOP*HD*4);
    float*    ps   = (float*)alloc((size_t)NPAIR*4);
    unsigned* pbc  = (unsigned*)alloc((size_t)NBLKP*4);
    unsigned* pbo  = (unsigned*)alloc((size_t)NBLKP*4);
    int*      pcnt = (int*)alloc(256);
    int*      pidx = (int*)alloc((size_t)NPAIR*4);
    ushort*   uw0T = (ushort*)alloc((size_t)HD*ED*2);
    ushort*   uw1T = (ushort*)alloc((size_t)HD*HD*2);
    ushort*   paT  = (ushort*)alloc((size_t)HD*ED*2);
    ushort*   pbT  = (ushort*)alloc((size_t)HD*ED*2);
    ushort*   pcT  = (ushort*)alloc((size_t)HD*ED*2);
    ushort*   pw1T = (ushort*)alloc((size_t)HD*HD*2);
    size_t fixed = off;
    size_t avail = ws_size > fixed ? ws_size - fixed : 0;

    // ---- weight prep: transpose + bf16 convert ----
    wt_k<<<dim3(HD/32, ED/32), 256, 0, stream>>>(uw0, uw0T, ED, HD);
    wt_k<<<dim3(HD/32, HD/32), 256, 0, stream>>>(uw1, uw1T, HD, HD);
    wt_k<<<dim3(HD/32, ED/32), 256, 0, stream>>>(pw0, paT, ED, HD);
    wt_k<<<dim3(HD/32, ED/32), 256, 0, stream>>>(pw0 + (size_t)ED*HD, pbT, ED, HD);
    wt_k<<<dim3(HD/32, ED/32), 256, 0, stream>>>(pw0 + (size_t)2*ED*HD, pcT, ED, HD);
    wt_k<<<dim3(HD/32, HD/32), 256, 0, stream>>>(pw1, pw1T, HD, HD);

    // ---- unary FFNN over all candidates: L1 (EPI=2) + L2 fused score (EPI=4) ----
    {
        long Rl = (long)(avail / 3584);      // embB(1536)+H1b(2048) per row
        int R = (int)(Rl > 100096 ? 100096 : Rl);
        R &= ~127; if (R < 128) R = 128;
        ushort* embB = (ushort*)(ws + fixed);
        ushort* H1b  = embB + (size_t)R*ED;
        for (int r0 = 0; r0 < NC; r0 += R) {
            int rows = NC - r0 < R ? NC - r0 : R;
            int MP = (rows + 127)/128;
            conv_k<<<1024, 256, 0, stream>>>(emb + (size_t)r0*ED, embB, rows*192);
            bgemm_k<2><<<swz_grid(MP), 256, 0, stream>>>(embB, ED, uw0T, ED, H1b, HD,
                rows, ED, MP, ub0, nullptr, nullptr, 0, nullptr, nullptr,
                nullptr, nullptr);
            bgemm_k<4><<<swz_grid(MP), 256, 0, stream>>>(H1b, HD, uw1T, HD, nullptr, 0,
                rows, HD, MP, ub1, nullptr, nullptr, 0, uw2, partS,
                nullptr, nullptr);
            comb_k<<<(rows + 255)/256, 256, 0, stream>>>(partS, ub2, scoresA + r0, rows);
        }
    }

    // ---- exact top-KTOP selection on computed scores (ascending index order) ----
    init_sel_k<<<1, 256, 0, stream>>>(stateA, histA, topA, KTOP);
    for (int pass = 0; pass < 4; ++pass) {
        int shift = 24 - pass*8;
        hist_k<<<256, 256, 0, stream>>>(scoresA, NC, histA + pass*256, stateA, shift);
        select_k<<<1, 64, 0, stream>>>(histA + pass*256, stateA, shift, KTOP);
    }
    cnt_k<<<NBLKA, 256, 0, stream>>>(scoresA, NC, stateA, gtA, eqA);
    scan_k<<<1, 64, 0, stream>>>(gtA, eqA, gtoA, eqoA, NBLKA, stateA, KTOP);
    write_k<<<NBLKA, 256, 0, stream>>>(scoresA, NC, stateA, gtoA, eqoA, topA, KTOP);
    gatherF_k<<<KTOP, 256, 0, stream>>>(emb, doc, topA, scoresA, meb, ms, mdoc);

    // ---- pair compaction: list of valid (in-window, same-doc) pairs ----
    pcnt_k<<<NBLKP, 256, 0, stream>>>(mdoc, pbc);
    pscan_k<<<1, 64, 0, stream>>>(pbc, pbo, pcnt);
    pwrite_k<<<NBLKP, 256, 0, stream>>>(mdoc, pbo, pidx);

    // ---- per-mention parts of pair layer 0 ----
    {
        int MP = (KTOP + 127)/128;
        bgemm_k<1><<<swz_grid(MP), 256, 0, stream>>>(meb, ED, paT, ED, U, HD, KTOP, ED,
            MP, pb0, nullptr, nullptr, 0, nullptr, nullptr, nullptr, nullptr);
        bgemm_k<0><<<swz_grid(MP), 256, 0, stream>>>(meb, ED, pbT, ED, V, HD, KTOP, ED,
            MP, nullptr, nullptr, nullptr, 0, nullptr, nullptr, nullptr, nullptr);
    }

    // ---- pairwise FFNN on COMPACTED pairs: L0 (EPI=3) + L1 fused score (EPI=4) ----
    {
        long Cl = (long)(avail / 3584);      // prod(1536)+h0(2048) per pair
        int Cp = (int)(Cl > NPAIR ? NPAIR : Cl);
        Cp &= ~127; if (Cp < 128) Cp = 128;
        ushort* prodb = (ushort*)(ws + fixed);
        ushort* h0b = prodb + (size_t)Cp*ED;
        for (int p0 = 0; p0 < NPAIR; p0 += Cp) {
            int pc = NPAIR - p0 < Cp ? NPAIR - p0 : Cp;
            int MP = (pc + 127)/128;
            prodb_k<<<1024, 256, 0, stream>>>(meb, prodb, p0, pc, pcnt, pidx);
            bgemm_k<3><<<swz_grid(MP), 256, 0, stream>>>(prodb, ED, pcT, ED, h0b, HD,
                pc, ED, MP, nullptr, U, V, p0, nullptr, nullptr, pcnt, pidx);
            bgemm_k<4><<<swz_grid(MP), 256, 0, stream>>>(h0b, HD, pw1T, HD, nullptr, 0,
                pc, HD, MP, pb1, nullptr, nullptr, p0, pw2, partS, pcnt, nullptr);
            combp_k<<<(pc + 255)/256, 256, 0, stream>>>(partS, pb2, ps, pc, p0,
                                                        pcnt, pidx);
        }
    }

    // ---- final assembly ----
    assemble_k<<<(KTOP*(AA+1) + 255)/256, 256, 0, stream>>>(ps, ms, mdoc, out);
}